// Round 1
// baseline (476.156 us; speedup 1.0000x reference)
//
#include <hip/hip_runtime.h>

// RGCN, pruned to the 2-hop dependency cone of the first 1024 nodes.
// Pipeline: flags/compaction -> gathered GEMM (linear1+relu) -> scatter-mean
// per relation -> concat GEMM (conv1) -> scatter-mean -> concat GEMM (conv2)
// -> GEMM (linear2+relu) -> per-row classifier dot.

#define N_NODES 100000
#define N_EDGES 400000
#define IN_DIM  768
#define HID     256
#define OUT_DIM 128
#define NREL    3
#define BATCH   1024
#define KCAT    1024   // HID*(NREL+1)
#define CAP0    32768  // capacity for |S0| (~22K expected)
#define CAP1    8192   // capacity for |S1| (~5K expected)

static __device__ __forceinline__ int imin(int a, int b) { return a < b ? a : b; }

// ---------------- set construction ----------------

__global__ void init_need1(int* need1) {
    int i = blockIdx.x * blockDim.x + threadIdx.x;
    if (i < N_NODES) need1[i] = (i < BATCH) ? 1 : 0;
}

__global__ void mark1(const int* __restrict__ ei, int* __restrict__ need1) {
    int e = blockIdx.x * blockDim.x + threadIdx.x;
    if (e >= N_EDGES) return;
    int d = ei[N_EDGES + e];
    if (d < BATCH) need1[ei[e]] = 1;   // benign same-value race
}

__global__ void init_need0(const int* __restrict__ map1, int* __restrict__ need0) {
    int i = blockIdx.x * blockDim.x + threadIdx.x;
    if (i < N_NODES) need0[i] = (map1[i] >= 0) ? 1 : 0;
}

__global__ void mark0(const int* __restrict__ ei, const int* __restrict__ map1,
                      int* __restrict__ need0) {
    int e = blockIdx.x * blockDim.x + threadIdx.x;
    if (e >= N_EDGES) return;
    if (map1[ei[N_EDGES + e]] >= 0) need0[ei[e]] = 1;
}

__global__ void compact(const int* __restrict__ flag, int* __restrict__ idx,
                        int* __restrict__ map, int* __restrict__ ctr, int cap) {
    int i = blockIdx.x * blockDim.x + threadIdx.x;
    if (i >= N_NODES) return;
    if (flag[i]) {
        int p = atomicAdd(ctr, 1);
        if (p < cap) { idx[p] = i; map[i] = p; }
        else map[i] = -1;
    } else {
        map[i] = -1;
    }
}

// ---------------- gathers ----------------

// Acat[j][0:256] = hsrc[mapSrc[idx[j]]][:]   for j < n
__global__ void gather_rows(const float* __restrict__ hsrc,
                            const int* __restrict__ idx, const int* __restrict__ mapSrc,
                            float* __restrict__ Acat,
                            const int* __restrict__ nptr, int cap) {
    int j = blockIdx.x, c = threadIdx.x;
    int n = imin(*nptr, cap);
    if (j >= n) return;
    int srow = mapSrc[idx[j]];
    Acat[(size_t)j * KCAT + c] = (srow >= 0) ? hsrc[(size_t)srow * HID + c] : 0.0f;
}

// Acat2[i][0:256] = h1c[map1[i]][:]   for i < BATCH (node id == row id)
__global__ void gather_rows_s2(const float* __restrict__ h1c, const int* __restrict__ map1,
                               float* __restrict__ Acat2) {
    int i = blockIdx.x, c = threadIdx.x;
    int srow = map1[i];
    Acat2[(size_t)i * KCAT + c] = (srow >= 0) ? h1c[(size_t)srow * HID + c] : 0.0f;
}

// ---------------- scatter (message aggregation) ----------------
// 64 lanes per edge; adds hsrc[src] into Acat[row][256 + r*256 + :], counts edges.
__global__ void scatter_msgs(const int* __restrict__ ei, const int* __restrict__ et,
                             const int* __restrict__ mapSrc, const int* __restrict__ mapDst,
                             const float* __restrict__ hsrc,
                             float* __restrict__ Acat, float* __restrict__ cnt,
                             int cntStride, int dstDirect) {
    int g = blockIdx.x * blockDim.x + threadIdx.x;
    int e = g >> 6, lane = g & 63;
    if (e >= N_EDGES) return;
    int d = ei[N_EDGES + e];
    int row = dstDirect ? ((d < BATCH) ? d : -1) : mapDst[d];
    if (row < 0) return;
    int s = mapSrc[ei[e]];
    if (s < 0) return;
    int r = et[e];
    const float* sp = hsrc + (size_t)s * HID;
    float* dp = Acat + (size_t)row * KCAT + HID + (size_t)r * HID;
    for (int c = lane; c < HID; c += 64) atomicAdd(dp + c, sp[c]);
    if (lane == 0) atomicAdd(cnt + (size_t)r * cntStride + row, 1.0f);
}

// divide each relation block by max(cnt,1)
__global__ void normalize_msgs(float* __restrict__ Acat, const float* __restrict__ cnt,
                               int cntStride, const int* __restrict__ nptr, int cap) {
    int j = blockIdx.x, c = threadIdx.x;
    int n = nptr ? imin(*nptr, cap) : cap;
    if (j >= n) return;
    #pragma unroll
    for (int r = 0; r < NREL; r++) {
        float f = cnt[(size_t)r * cntStride + j];
        float s = 1.0f / fmaxf(f, 1.0f);
        Acat[(size_t)j * KCAT + HID + (size_t)r * HID + c] *= s;
    }
}

// ---------------- fp32 tiled GEMM: C = op(A) @ B + bias, optional relu ----------------
// BM=BN=64, BK=16, 256 threads, 4x4 per thread. K, N multiples of 16/64.
template<bool GATHER, bool RELU>
__global__ __launch_bounds__(256) void gemm_f32(
    const float* __restrict__ A, int lda,
    const int* __restrict__ gidx,
    const float* __restrict__ B, int ldb,
    const float* __restrict__ bias,
    float* __restrict__ C, int ldc,
    const int* __restrict__ Mptr, int Mcap, int K)
{
    constexpr int BM = 64, BN = 64, BK = 16;
    int M = Mptr ? imin(*Mptr, Mcap) : Mcap;
    int bm = blockIdx.x * BM;
    int bn = blockIdx.y * BN;
    if (bm >= M) return;

    __shared__ float As[BK][BM + 4];
    __shared__ float Bs[BK][BN + 4];

    int tid = threadIdx.x;
    int tx = tid & 15, ty = tid >> 4;
    int arow = tid >> 2, akch = tid & 3;   // A: 64 rows x 4 float4-chunks
    int brow = tid >> 4, bnch = tid & 15;  // B: 16 k-rows x 16 float4-chunks

    bool rowok = (bm + arow) < M;
    int grow = 0;
    if (rowok) grow = GATHER ? gidx[bm + arow] : (bm + arow);
    const float* Aptr = A + (size_t)grow * lda + akch * 4;
    const float* Bptr = B + (size_t)brow * ldb + bn + bnch * 4;

    float acc[4][4] = {};

    for (int k0 = 0; k0 < K; k0 += BK) {
        float4 av = rowok ? *(const float4*)(Aptr + k0) : make_float4(0.f, 0.f, 0.f, 0.f);
        float4 bv = *(const float4*)(Bptr + (size_t)k0 * ldb);
        As[akch * 4 + 0][arow] = av.x;
        As[akch * 4 + 1][arow] = av.y;
        As[akch * 4 + 2][arow] = av.z;
        As[akch * 4 + 3][arow] = av.w;
        *(float4*)&Bs[brow][bnch * 4] = bv;
        __syncthreads();
        #pragma unroll
        for (int k = 0; k < BK; k++) {
            float4 a = *(const float4*)&As[k][ty * 4];
            float4 b = *(const float4*)&Bs[k][tx * 4];
            acc[0][0] += a.x * b.x; acc[0][1] += a.x * b.y; acc[0][2] += a.x * b.z; acc[0][3] += a.x * b.w;
            acc[1][0] += a.y * b.x; acc[1][1] += a.y * b.y; acc[1][2] += a.y * b.z; acc[1][3] += a.y * b.w;
            acc[2][0] += a.z * b.x; acc[2][1] += a.z * b.y; acc[2][2] += a.z * b.z; acc[2][3] += a.z * b.w;
            acc[3][0] += a.w * b.x; acc[3][1] += a.w * b.y; acc[3][2] += a.w * b.z; acc[3][3] += a.w * b.w;
        }
        __syncthreads();
    }

    #pragma unroll
    for (int i = 0; i < 4; i++) {
        int row = bm + ty * 4 + i;
        if (row < M) {
            int col = bn + tx * 4;
            float4 o;
            o.x = acc[i][0] + bias[col + 0];
            o.y = acc[i][1] + bias[col + 1];
            o.z = acc[i][2] + bias[col + 2];
            o.w = acc[i][3] + bias[col + 3];
            if (RELU) {
                o.x = fmaxf(o.x, 0.f); o.y = fmaxf(o.y, 0.f);
                o.z = fmaxf(o.z, 0.f); o.w = fmaxf(o.w, 0.f);
            }
            *(float4*)&C[(size_t)row * ldc + col] = o;
        }
    }
}

// ---------------- classifier: out[row][0:2] = h3[row] @ Wc + bc ----------------
__global__ void classifier_k(const float* __restrict__ h3, const float* __restrict__ Wc,
                             const float* __restrict__ bc, float* __restrict__ out) {
    int row = blockIdx.x;
    int t = threadIdx.x;   // 64 lanes
    const float* hp = h3 + (size_t)row * OUT_DIM;
    float a = hp[t], b = hp[t + 64];
    float s0 = a * Wc[t * 2 + 0] + b * Wc[(t + 64) * 2 + 0];
    float s1 = a * Wc[t * 2 + 1] + b * Wc[(t + 64) * 2 + 1];
    #pragma unroll
    for (int o = 32; o >= 1; o >>= 1) {
        s0 += __shfl_xor(s0, o);
        s1 += __shfl_xor(s1, o);
    }
    if (t == 0) {
        out[row * 2 + 0] = s0 + bc[0];
        out[row * 2 + 1] = s1 + bc[1];
    }
}

// ---------------- host ----------------

extern "C" void kernel_launch(void* const* d_in, const int* in_sizes, int n_in,
                              void* d_out, int out_size, void* d_ws, size_t ws_size,
                              hipStream_t stream) {
    const float* x      = (const float*)d_in[0];
    const int*   ei     = (const int*)d_in[1];
    const int*   et     = (const int*)d_in[2];
    // d_in[3] = batch_size (1024, hard-coded)
    const float* W1     = (const float*)d_in[4];
    const float* b1     = (const float*)d_in[5];
    const float* c1W    = (const float*)d_in[6];
    const float* c1root = (const float*)d_in[7];
    const float* c1bias = (const float*)d_in[8];
    const float* c2W    = (const float*)d_in[9];
    const float* c2root = (const float*)d_in[10];
    const float* c2bias = (const float*)d_in[11];
    const float* W2     = (const float*)d_in[12];
    const float* b2     = (const float*)d_in[13];
    const float* Wc     = (const float*)d_in[14];
    const float* bc     = (const float*)d_in[15];
    float* out = (float*)d_out;

    char* ws = (char*)d_ws;
    size_t off = 0;
    auto alloc = [&](size_t bytes) -> char* {
        char* p = ws + off;
        off = (off + bytes + 255) & ~(size_t)255;
        return p;
    };

    int* need1 = (int*)alloc(N_NODES * 4);
    int* need0 = (int*)alloc(N_NODES * 4);
    int* map1  = (int*)alloc(N_NODES * 4);
    int* map0  = (int*)alloc(N_NODES * 4);
    int* idx1  = (int*)alloc(CAP1 * 4);
    int* idx0  = (int*)alloc(CAP0 * 4);
    // contiguous zero block: counters + relation counts
    size_t zbytes = 2 * 4 + (size_t)NREL * CAP1 * 4 + (size_t)NREL * BATCH * 4;
    char* zblock = alloc(zbytes);
    int*   n1ctr = (int*)zblock;
    int*   n0ctr = n1ctr + 1;
    float* cnt1  = (float*)(zblock + 8);
    float* cnt2  = cnt1 + (size_t)NREL * CAP1;
    float* h0c   = (float*)alloc((size_t)CAP0 * HID * 4);
    float* Acat1 = (float*)alloc((size_t)CAP1 * KCAT * 4);
    float* h1c   = (float*)alloc((size_t)CAP1 * HID * 4);
    float* Acat2 = (float*)alloc((size_t)BATCH * KCAT * 4);
    float* h2    = (float*)alloc((size_t)BATCH * HID * 4);
    float* h3    = (float*)alloc((size_t)BATCH * OUT_DIM * 4);
    float* Bcat1 = (float*)alloc((size_t)KCAT * HID * 4);
    float* Bcat2 = (float*)alloc((size_t)KCAT * HID * 4);
    (void)ws_size; (void)in_sizes; (void)n_in; (void)out_size;

    const int NB = 256;
    dim3 nodeGrid((N_NODES + NB - 1) / NB);
    dim3 edgeGrid((N_EDGES + NB - 1) / NB);
    dim3 scatGrid((N_EDGES * 64) / NB);   // 64 lanes per edge

    // zero counters/counts and scatter targets; build concat-B matrices
    hipMemsetAsync(zblock, 0, zbytes, stream);
    hipMemsetAsync(Acat1, 0, (size_t)CAP1 * KCAT * 4, stream);
    hipMemsetAsync(Acat2, 0, (size_t)BATCH * KCAT * 4, stream);
    hipMemcpyAsync(Bcat1, c1root, (size_t)HID * HID * 4, hipMemcpyDeviceToDevice, stream);
    hipMemcpyAsync(Bcat1 + (size_t)HID * HID, c1W, (size_t)NREL * HID * HID * 4, hipMemcpyDeviceToDevice, stream);
    hipMemcpyAsync(Bcat2, c2root, (size_t)HID * HID * 4, hipMemcpyDeviceToDevice, stream);
    hipMemcpyAsync(Bcat2 + (size_t)HID * HID, c2W, (size_t)NREL * HID * HID * 4, hipMemcpyDeviceToDevice, stream);

    // dependency cone: S1 = S2 ∪ src(edges into S2), S0 = S1 ∪ src(edges into S1)
    init_need1<<<nodeGrid, NB, 0, stream>>>(need1);
    mark1<<<edgeGrid, NB, 0, stream>>>(ei, need1);
    compact<<<nodeGrid, NB, 0, stream>>>(need1, idx1, map1, n1ctr, CAP1);
    init_need0<<<nodeGrid, NB, 0, stream>>>(map1, need0);
    mark0<<<edgeGrid, NB, 0, stream>>>(ei, map1, need0);
    compact<<<nodeGrid, NB, 0, stream>>>(need0, idx0, map0, n0ctr, CAP0);

    // h0c = relu(x[S0] @ W1 + b1)
    gemm_f32<true, true><<<dim3(CAP0 / 64, HID / 64), NB, 0, stream>>>(
        x, IN_DIM, idx0, W1, HID, b1, h0c, HID, n0ctr, CAP0, IN_DIM);

    // conv1: Acat1 = [h0(S1 rows) | mean-agg per relation]; h1c = Acat1 @ Bcat1 + bias
    gather_rows<<<dim3(CAP1), NB, 0, stream>>>(h0c, idx1, map0, Acat1, n1ctr, CAP1);
    scatter_msgs<<<scatGrid, NB, 0, stream>>>(ei, et, map0, map1, h0c, Acat1, cnt1, CAP1, 0);
    normalize_msgs<<<dim3(CAP1), NB, 0, stream>>>(Acat1, cnt1, CAP1, n1ctr, CAP1);
    gemm_f32<false, false><<<dim3(CAP1 / 64, HID / 64), NB, 0, stream>>>(
        Acat1, KCAT, nullptr, Bcat1, HID, c1bias, h1c, HID, n1ctr, CAP1, KCAT);

    // conv2 (output rows = node ids 0..1023)
    gather_rows_s2<<<dim3(BATCH), NB, 0, stream>>>(h1c, map1, Acat2);
    scatter_msgs<<<scatGrid, NB, 0, stream>>>(ei, et, map1, nullptr, h1c, Acat2, cnt2, BATCH, 1);
    normalize_msgs<<<dim3(BATCH), NB, 0, stream>>>(Acat2, cnt2, BATCH, nullptr, BATCH);
    gemm_f32<false, false><<<dim3(BATCH / 64, HID / 64), NB, 0, stream>>>(
        Acat2, KCAT, nullptr, Bcat2, HID, c2bias, h2, HID, nullptr, BATCH, KCAT);

    // h3 = relu(h2 @ W2 + b2); logits = h3 @ Wc + bc
    gemm_f32<false, true><<<dim3(BATCH / 64, OUT_DIM / 64), NB, 0, stream>>>(
        h2, HID, nullptr, W2, OUT_DIM, b2, h3, OUT_DIM, nullptr, BATCH, HID);
    classifier_k<<<dim3(BATCH), 64, 0, stream>>>(h3, Wc, bc, out);
}